// Round 2
// baseline (87.675 us; speedup 1.0000x reference)
//
#include <hip/hip_runtime.h>
#include <math.h>

// Problem constants (fixed by setup_inputs): N src points, M targets, D=3.
constexpr int N_SRC = 16384;
constexpr int M_TAR = 16384;

// R7: same instruction-exact pair cost as R5/R6 (4.5 VALU ops/pair:
// 3 v_fma_f32 + 1 v_and_or_b32 + 0.5 v_min3_f32) but targets-per-thread
// doubled 8 -> 16. Total LDS reads = M*N/tpt, so ds_read_b128 traffic per
// CU HALVES (2048 -> 1024 wave-ops). This needs 64 VGPRs of target state,
// so we move to the 128-VGPR occupancy tier: 512-thread blocks, 2/CU
// (16 waves/CU = 4 waves/SIMD), which also unchokes the register
// allocator (R6 ran at the 64-reg cap with ~60 live values).
//   - g = tid>>8: each wave reads 64 DISTINCT contiguous float4s from LDS
//     (the exact pattern measured at ~12 cyc/b128), no broadcast aliasing.
//   - double-buffered LDS + prefetch-issue-before-compute kept from R6
//     (one barrier per tile).
//   - tile loop NOT unrolled (body ~6 KB, I$-resident, low reg pressure);
//     i/k loops fully unrolled (imm ds offsets within a tile).
constexpr int BLOCKS = 512;            // 32 targets per block
constexpr int TPB = 512;               // 8 waves
constexpr int CHUNKS = 256;            // chunk = tid & 255
constexpr int TILE = 2048;             // sources per LDS tile (32 KB float4)
constexpr int TILES = N_SRC / TILE;    // 8
constexpr int ROWS_PT = TILE / CHUNKS; // 8 rows per tile
constexpr int IPT = ROWS_PT / 2;       // 4 source-pairs per tile per thread
constexpr int TPT = 16;                // targets per thread
constexpr int PPT = TILE / TPB;        // 4 staged points per thread per tile

__global__ void zero_out(float* __restrict__ out) {
    if (threadIdx.x == 0) out[0] = 0.0f;  // d_out poisoned 0xAA each launch
}

// (t & mask_v) | row_s  — mask forced to VGPR, uniform row rides the SGPR slot
__device__ __forceinline__ float embed_ao(float t, unsigned mask_v, unsigned row_s) {
    float r;
    asm("v_and_or_b32 %0, %1, %2, %3"
        : "=v"(r) : "v"(t), "v"(mask_v), "s"(row_s));
    return r;
}
// best = min(best, e0, e1) in one instruction (inputs never NaN here)
__device__ __forceinline__ void min3(float& b, float e0, float e1) {
    asm("v_min3_f32 %0, %0, %1, %2"
        : "+v"(b) : "v"(e0), "v"(e1));
}

__global__ __launch_bounds__(TPB, 4) void nn8(const float* __restrict__ src,
                                              const float* __restrict__ tar,
                                              float* __restrict__ out) {
    __shared__ float4 tile[2 * TILE];  // 64 KB double buffer; reused in tail

    const int tid   = threadIdx.x;
    const int g     = tid >> 8;     // 0..1: target half owned by this thread
    const int chunk = tid & 255;    // 0..255: source slice
    const int tbase = blockIdx.x * 32;

    // 16 targets/thread, premultiplied by -2 so ||s||^2 folds into the fmas
    float txm2[TPT], tym2[TPT], tzm2[TPT], best[TPT];
#pragma unroll
    for (int k = 0; k < TPT; ++k) {
        int T = tbase + g * TPT + k;
        txm2[k] = -2.0f * tar[3 * T + 0];
        tym2[k] = -2.0f * tar[3 * T + 1];
        tzm2[k] = -2.0f * tar[3 * T + 2];
        best[k] = INFINITY;
    }

    // ---- prolog: stage tile 0
#pragma unroll
    for (int r = 0; r < PPT; ++r) {
        int p = tid + r * TPB;
        const float* q = src + 3 * p;
        float x = q[0], y = q[1], z = q[2];
        tile[p] = make_float4(x, y, z, fmaf(x, x, fmaf(y, y, z * z)));
    }
    __syncthreads();

    unsigned mask_v = 0xFFFFFFC0u;  // lives in a VGPR for v_and_or_b32

    auto compute = [&](int cb, unsigned rowbase) {
#pragma unroll
        for (int i = 0; i < IPT; ++i) {
            float4 s0 = tile[cb + (2 * i + 0) * CHUNKS + chunk];
            float4 s1 = tile[cb + (2 * i + 1) * CHUNKS + chunk];
            unsigned row0 = rowbase + 2 * i;      // uniform (SGPR)
            unsigned row1 = rowbase + 2 * i + 1;  // uniform (SGPR)
#pragma unroll
            for (int k = 0; k < TPT; ++k) {
                float t0 = fmaf(s0.z, tzm2[k], s0.w);
                t0 = fmaf(s0.y, tym2[k], t0);
                t0 = fmaf(s0.x, txm2[k], t0);
                float t1 = fmaf(s1.z, tzm2[k], s1.w);
                t1 = fmaf(s1.y, tym2[k], t1);
                t1 = fmaf(s1.x, txm2[k], t1);
                float e0 = embed_ao(t0, mask_v, row0);
                float e1 = embed_ao(t1, mask_v, row1);
                min3(best[k], e0, e1);
            }
        }
    };

    // ---- pipelined main loop: prefetch tl+1, compute tl, write tl+1
#pragma unroll 1
    for (int tl = 0; tl < TILES - 1; ++tl) {
        float px[PPT], py[PPT], pz[PPT];
#pragma unroll
        for (int r = 0; r < PPT; ++r) {
            const float* q = src + 3 * ((tl + 1) * TILE + tid + r * TPB);
            px[r] = q[0]; py[r] = q[1]; pz[r] = q[2];
        }
        __builtin_amdgcn_sched_barrier(0);  // keep load issues above compute

        compute((tl & 1) * TILE, (unsigned)(tl * ROWS_PT));

        const int wb = ((tl + 1) & 1) * TILE;
#pragma unroll
        for (int r = 0; r < PPT; ++r) {
            float x = px[r], y = py[r], z = pz[r];
            tile[wb + tid + r * TPB] =
                make_float4(x, y, z, fmaf(x, x, fmaf(y, y, z * z)));
        }
        __syncthreads();  // publishes writes for tl+1; retires reads of tl
    }
    compute(((TILES - 1) & 1) * TILE, (unsigned)((TILES - 1) * ROWS_PT));

    // ---- tail: resolve indices, merge 256 chunks per target, loss, atomic
    __syncthreads();                     // all compute reads of tile done
    float* fv = (float*)tile;            // [32][256] values  (32 KB)
    int*   fj = (int*)tile + 32 * 256;   // [32][256] indices (32 KB)
#pragma unroll
    for (int k = 0; k < TPT; ++k) {
        unsigned b = __float_as_uint(best[k]);
        int j  = (int)((b & 63u) * CHUNKS + chunk);  // j = row*256 + chunk
        int lt = g * TPT + k;
        fv[lt * CHUNKS + chunk] = __uint_as_float(b & 0xFFFFFFC0u);
        fj[lt * CHUNKS + chunk] = j;
    }
    __syncthreads();

    const int tprime = tid >> 4;   // 0..31: target this 16-lane group reduces
    const int sub    = tid & 15;
    float bv = fv[tprime * CHUNKS + sub];
    int   bj = fj[tprime * CHUNKS + sub];
#pragma unroll
    for (int m = 1; m < CHUNKS / 16; ++m) {
        float v = fv[tprime * CHUNKS + sub + 16 * m];
        int   j = fj[tprime * CHUNKS + sub + 16 * m];
        if (v < bv) { bv = v; bj = j; }
    }
#pragma unroll
    for (int s = 8; s >= 1; s >>= 1) {   // xor<16 stays in the 16-lane group
        float vv = __shfl_xor(bv, s, 64);
        int   jj = __shfl_xor(bj, s, 64);
        if (vv < bv) { bv = vv; bj = jj; }
    }
    __syncthreads();  // done reading fv/fj; safe to reuse

    if (sub == 0) {
        int tt = tbase + tprime;
        // exact loss term from the winning index (reference formula)
        float dx = src[3 * bj + 0] - tar[3 * tt + 0];
        float dy = src[3 * bj + 1] - tar[3 * tt + 1];
        float dz = src[3 * bj + 2] - tar[3 * tt + 2];
        fv[tprime] = 0.5f * fmaf(dx, dx, fmaf(dy, dy, dz * dz));
    }
    __syncthreads();
    if (tid == 0) {
        float ssum = 0.0f;
#pragma unroll
        for (int i = 0; i < 32; ++i) ssum += fv[i];
        atomicAdd(out, ssum);  // device-scope, cross-XCD safe
    }
}

extern "C" void kernel_launch(void* const* d_in, const int* in_sizes, int n_in,
                              void* d_out, int out_size, void* d_ws, size_t ws_size,
                              hipStream_t stream) {
    const float* src = (const float*)d_in[0];  // src_V [N,3] fp32
    const float* tar = (const float*)d_in[1];  // tar_V [M,3] fp32
    float* out = (float*)d_out;                // scalar loss fp32
    (void)d_ws; (void)ws_size;

    zero_out<<<1, 64, 0, stream>>>(out);
    nn8<<<BLOCKS, TPB, 0, stream>>>(src, tar, out);
}